// Round 1
// baseline (81.271 us; speedup 1.0000x reference)
//
#include <hip/hip_runtime.h>
#include <math.h>

#define HW_   6688      // 44*152
#define H_    44
#define W_    152
#define B_    16
#define NPIX  107008    // 16*44*152
#define OW_   1216      // 152*8
#define OHW_  428032    // 352*1216

// transposed-weight offsets (floats) inside d_ws
#define OFF_W0 0        // 128*64
#define OFF_W1 8192     // 64*32
#define OFF_W2 10240    // 32*16
#define OFF_W3 10752    // 16*8
#define OFF_W4 10880    // 8*4
#define OFF_CW 10912    // 4*3

__device__ __forceinline__ float fast_sigmoid(float x) {
    return __builtin_amdgcn_rcpf(1.0f + __expf(-x));
}
__device__ __forceinline__ float eluf(float x) {
    return x > 0.0f ? x : (__expf(x) - 1.0f);
}

// Dense layer on register arrays. Weights are transposed [cin][cout] so the
// unrolled o-loop reads contiguous floats -> compiler emits vector s_load.
template<int CIN, int COUT, bool ELU>
__device__ __forceinline__ void dense(const float* __restrict__ wt,
                                      const float* __restrict__ bias,
                                      const float (&in)[CIN], float (&out)[COUT]) {
#pragma unroll
    for (int o = 0; o < COUT; ++o) out[o] = bias[o];
#pragma unroll
    for (int c = 0; c < CIN; ++c) {
#pragma unroll
        for (int o = 0; o < COUT; ++o)
            out[o] = fmaf(wt[c * COUT + o], in[c], out[o]);
    }
    if (ELU) {
#pragma unroll
        for (int o = 0; o < COUT; ++o) out[o] = eluf(out[o]);
    }
}

// Transpose all weights (cout,cin) -> (cin,cout) into workspace.
__global__ void prep_weights(const float* __restrict__ w0, const float* __restrict__ w1,
                             const float* __restrict__ w2, const float* __restrict__ w3,
                             const float* __restrict__ w4, const float* __restrict__ cw,
                             float* __restrict__ ws) {
    int t = blockIdx.x * blockDim.x + threadIdx.x;
    int stride = gridDim.x * blockDim.x;
    for (int i = t; i < 64 * 128; i += stride) { int o = i >> 7, c = i & 127; ws[OFF_W0 + c * 64 + o] = w0[i]; }
    for (int i = t; i < 32 * 64;  i += stride) { int o = i >> 6, c = i & 63;  ws[OFF_W1 + c * 32 + o] = w1[i]; }
    for (int i = t; i < 16 * 32;  i += stride) { int o = i >> 5, c = i & 31;  ws[OFF_W2 + c * 16 + o] = w2[i]; }
    for (int i = t; i < 8 * 16;   i += stride) { int o = i >> 4, c = i & 15;  ws[OFF_W3 + c * 8  + o] = w3[i]; }
    for (int i = t; i < 4 * 8;    i += stride) { int o = i >> 3, c = i & 7;   ws[OFF_W4 + c * 4  + o] = w4[i]; }
    for (int i = t; i < 3 * 4;    i += stride) { int o = i >> 2, c = i & 3;   ws[OFF_CW + c * 3  + o] = cw[i]; }
}

__global__ __launch_bounds__(64)
void lpg_fused(const float* __restrict__ x, const float* __restrict__ wt,
               const float* __restrict__ b0, const float* __restrict__ b1,
               const float* __restrict__ b2, const float* __restrict__ b3,
               const float* __restrict__ b4, const float* __restrict__ cb,
               float* __restrict__ out) {
    int pix = blockIdx.x * 64 + threadIdx.x;
    if (pix >= NPIX) return;
    int b  = pix / HW_;
    int hw = pix - b * HW_;
    int h  = hw / W_;
    int w  = hw - h * W_;
    const float* xb = x + (size_t)b * 128 * HW_ + hw;

    const float* wt0 = wt + OFF_W0;
    const float* wt1 = wt + OFF_W1;
    const float* wt2 = wt + OFF_W2;
    const float* wt3 = wt + OFF_W3;
    const float* wt4 = wt + OFF_W4;
    const float* cwt = wt + OFF_CW;

    // ---- layer 0: 128 -> 64, x streamed from global (coalesced across lanes)
    float a0[64];
#pragma unroll
    for (int o = 0; o < 64; ++o) a0[o] = b0[o];
#pragma unroll 2
    for (int c = 0; c < 128; ++c) {
        float xv = xb[c * HW_];
#pragma unroll
        for (int o = 0; o < 64; ++o)
            a0[o] = fmaf(wt0[c * 64 + o], xv, a0[o]);
    }
#pragma unroll
    for (int o = 0; o < 64; ++o) a0[o] = eluf(a0[o]);

    // ---- layers 1..4 on register arrays
    float a1[32]; dense<64, 32, true>(wt1, b1, a0, a1);
    float a2[16]; dense<32, 16, true>(wt2, b2, a1, a2);
    float a3[8];  dense<16, 8,  true>(wt3, b3, a2, a3);
    float a4[4];  dense<8,  4,  true>(wt4, b4, a3, a4);

    // ---- head: 4 -> 3 (no activation)
    float y[3];
#pragma unroll
    for (int k = 0; k < 3; ++k) y[k] = cb[k];
#pragma unroll
    for (int c = 0; c < 4; ++c) {
#pragma unroll
        for (int k = 0; k < 3; ++k)
            y[k] = fmaf(cwt[c * 3 + k], a4[c], y[k]);
    }

    // ---- plane parameters
    float theta = 0.5235987756f * fast_sigmoid(y[0]);   // pi/6
    float phi   = 6.2831853072f * fast_sigmoid(y[1]);   // 2*pi
    float dist  = 83.0f         * fast_sigmoid(y[2]);
    float st = __sinf(theta), ct = __cosf(theta);
    float sp = __sinf(phi),   cp = __cosf(phi);
    float n1 = st * cp, n2 = st * sp, n3 = ct;
    float inv = __frsqrt_rn(fmaf(n1, n1, fmaf(n2, n2, n3 * n3)));
    n1 *= inv; n2 *= inv; n3 *= inv;

    // ---- 8x8 depth expansion
    const float ksc = 1.0f / (8.0f * 715.0f);
    float nu[8];
#pragma unroll
    for (int j = 0; j < 8; ++j) {
        float off = ((float)j - 3.5f) * ksc;
        nu[j] = n1 * off;
    }
    int obase = b * OHW_ + (h * 8) * OW_ + w * 8;
#pragma unroll
    for (int i = 0; i < 8; ++i) {
        float offv = ((float)i - 3.5f) * ksc;
        float base = fmaf(n2, offv, n3);
        float4 r0, r1;
        r0.x = dist * __builtin_amdgcn_rcpf(base + nu[0]);
        r0.y = dist * __builtin_amdgcn_rcpf(base + nu[1]);
        r0.z = dist * __builtin_amdgcn_rcpf(base + nu[2]);
        r0.w = dist * __builtin_amdgcn_rcpf(base + nu[3]);
        r1.x = dist * __builtin_amdgcn_rcpf(base + nu[4]);
        r1.y = dist * __builtin_amdgcn_rcpf(base + nu[5]);
        r1.z = dist * __builtin_amdgcn_rcpf(base + nu[6]);
        r1.w = dist * __builtin_amdgcn_rcpf(base + nu[7]);
        float4* op = (float4*)(out + obase + i * OW_);
        op[0] = r0;
        op[1] = r1;
    }
}

extern "C" void kernel_launch(void* const* d_in, const int* in_sizes, int n_in,
                              void* d_out, int out_size, void* d_ws, size_t ws_size,
                              hipStream_t stream) {
    const float* x  = (const float*)d_in[0];
    const float* w0 = (const float*)d_in[1];
    const float* b0 = (const float*)d_in[2];
    const float* w1 = (const float*)d_in[3];
    const float* b1 = (const float*)d_in[4];
    const float* w2 = (const float*)d_in[5];
    const float* b2 = (const float*)d_in[6];
    const float* w3 = (const float*)d_in[7];
    const float* b3 = (const float*)d_in[8];
    const float* w4 = (const float*)d_in[9];
    const float* b4 = (const float*)d_in[10];
    const float* cw = (const float*)d_in[11];
    const float* cb = (const float*)d_in[12];
    float* ws  = (float*)d_ws;
    float* out = (float*)d_out;

    prep_weights<<<16, 256, 0, stream>>>(w0, w1, w2, w3, w4, cw, ws);
    lpg_fused<<<NPIX / 64, 64, 0, stream>>>(x, ws, b0, b1, b2, b3, b4, cb, out);
}